// Round 1
// baseline (108.576 us; speedup 1.0000x reference)
//
#include <hip/hip_runtime.h>

#define BATCH 8192
#define HIDDEN 8192
#define NUM_SEEDS 16
#define CHUNK 512          // HIDDEN / NUM_SEEDS
#define H4 (HIDDEN / 4)    // float4s per row

__global__ __launch_bounds__(256) void seed_layer_kernel(
    const float4* __restrict__ x4,
    const int*    __restrict__ lifecycle,
    const int*    __restrict__ blueprint,
    const int*    __restrict__ strategy,
    const float*  __restrict__ weights,
    float4*       __restrict__ out4,
    long long n4)
{
    // Per-seed coefficient LUT: out = cx*x + cw*w + cm*(x*w)
    __shared__ float s_cx[NUM_SEEDS];
    __shared__ float s_cw[NUM_SEEDS];
    __shared__ float s_cm[NUM_SEEDS];
    __shared__ int   s_bp[NUM_SEEDS];

    if (threadIdx.x < NUM_SEEDS) {
        const int s    = threadIdx.x;
        const int life = lifecycle[s];
        const int strt = strategy[s];
        const bool active = (life >= 3) && (life <= 6);
        float cx, cw, cm;
        if (!active)         { cx = 1.0f; cw = 0.0f; cm = 0.0f; }
        else if (strt == 0)  { cx = 0.0f; cw = 0.0f; cm = 1.0f; }  // x*w
        else if (strt == 1)  { cx = 1.0f; cw = 1.0f; cm = 0.0f; }  // x+w
        else                 { cx = 0.5f; cw = 0.5f; cm = 0.0f; }  // 0.5x+0.5w
        s_cx[s] = cx; s_cw[s] = cw; s_cm[s] = cm;
        s_bp[s] = blueprint[s];
    }
    __syncthreads();

    long long i      = (long long)blockIdx.x * blockDim.x + threadIdx.x;
    const long long stride = (long long)gridDim.x * blockDim.x;

    for (; i < n4; i += stride) {
        const int h4  = (int)(i & (H4 - 1));     // float4 index within a row
        const int sid = (h4 * 4) >> 9;           // feature chunk -> seed id (wave-uniform)

        const float cx = s_cx[sid];              // LDS broadcast (conflict-free)
        const float cw = s_cw[sid];
        const float cm = s_cm[sid];
        const int   bp = s_bp[sid];

        const float4 xv = x4[i];
        const float4 wv = reinterpret_cast<const float4*>(
                              weights + (long long)bp * HIDDEN)[h4];

        float4 o;
        o.x = cx * xv.x + cw * wv.x + cm * (xv.x * wv.x);
        o.y = cx * xv.y + cw * wv.y + cm * (xv.y * wv.y);
        o.z = cx * xv.z + cw * wv.z + cm * (xv.z * wv.z);
        o.w = cx * xv.w + cw * wv.w + cm * (xv.w * wv.w);
        out4[i] = o;
    }
}

extern "C" void kernel_launch(void* const* d_in, const int* in_sizes, int n_in,
                              void* d_out, int out_size, void* d_ws, size_t ws_size,
                              hipStream_t stream) {
    const float4* x4        = (const float4*)d_in[0];
    const int*    lifecycle = (const int*)d_in[1];
    const int*    blueprint = (const int*)d_in[2];
    const int*    strategy  = (const int*)d_in[3];
    const float*  weights   = (const float*)d_in[4];
    // d_in[5] is chunk_size scalar (512) — compile-time constant here.

    float4* out4 = (float4*)d_out;
    const long long n4 = (long long)BATCH * HIDDEN / 4;  // 16,777,216

    const int block = 256;
    const int grid  = 2048;  // 256 CUs * 8 blocks/CU; grid-stride covers the rest

    seed_layer_kernel<<<grid, block, 0, stream>>>(
        x4, lifecycle, blueprint, strategy, weights, out4, n4);
}